// Round 5
// baseline (174.046 us; speedup 1.0000x reference)
//
#include <hip/hip_runtime.h>
#include <math.h>

typedef __attribute__((ext_vector_type(8))) short bf16x8;
typedef __attribute__((ext_vector_type(4))) float f32x4;
typedef __attribute__((ext_vector_type(4))) int int4v;

__device__ __forceinline__ ushort f2bf(float f) {
    union { float f; unsigned u; } v; v.f = f;
    unsigned r = (v.u + 0x7fffu + ((v.u >> 16) & 1u)) >> 16;
    return (ushort)r;
}
__device__ __forceinline__ float bf2f(ushort h) {
    union { unsigned u; float f; } v; v.u = ((unsigned)h) << 16;
    return v.f;
}

// ---------------------------------------------------------------------------
// Fused packs: z=0 pack concat(src0,src1)->xin1[px][128];
//              z=1 up2(l_off)*2 -> xin2[px][64:128]; z=2 up2(l_fea) -> xin4[px][64:128]
__global__ __launch_bounds__(256) void pack_combo_k(
        const float* __restrict__ s0, const float* __restrict__ s1,
        const float* __restrict__ lo, const float* __restrict__ lf,
        ushort* __restrict__ xin1, ushort* __restrict__ xin2,
        ushort* __restrict__ xin4) {
    int b = blockIdx.y;
    int z = blockIdx.z;
    int px = blockIdx.x * 64 + (threadIdx.x & 63);
    int u = threadIdx.x >> 6;
    if (z == 0) {
        for (int half = 0; half < 2; ++half) {
            int cg = u + half * 4;
            alignas(16) ushort tmp[16];
            for (int i = 0; i < 16; ++i) {
                int c = cg * 16 + i;
                float v = (c < 64) ? s0[((size_t)(b * 64 + c)) * 9216 + px]
                                   : s1[((size_t)(b * 64 + c - 64)) * 9216 + px];
                tmp[i] = f2bf(v);
            }
            ushort* dst = xin1 + ((size_t)(b * 9216) + px) * 128 + cg * 16;
            *(int4v*)dst = *(int4v*)&tmp[0];
            *(int4v*)(dst + 8) = *(int4v*)&tmp[8];
        }
    } else {
        const float* in = (z == 1) ? lo : lf;
        float scale = (z == 1) ? 2.0f : 1.0f;
        ushort* xo = (z == 1) ? xin2 : xin4;
        int y = px / 96, x = px % 96;
        float sy = fmaxf(y * 0.5f - 0.25f, 0.f);
        float sx = fmaxf(x * 0.5f - 0.25f, 0.f);
        int y0 = (int)sy, x0 = (int)sx;
        float ty = sy - (float)y0, tx = sx - (float)x0;
        int y1 = min(y0 + 1, 47), x1 = min(x0 + 1, 47);
        alignas(16) ushort tmp[16];
        for (int i = 0; i < 16; ++i) {
            int c = u * 16 + i;
            const float* p = in + ((size_t)(b * 64 + c)) * 2304;
            float v00 = p[y0 * 48 + x0], v01 = p[y0 * 48 + x1];
            float v10 = p[y1 * 48 + x0], v11 = p[y1 * 48 + x1];
            float v = (v00 * (1.f - tx) + v01 * tx) * (1.f - ty)
                    + (v10 * (1.f - tx) + v11 * tx) * ty;
            tmp[i] = f2bf(v * scale);
        }
        ushort* dst = xo + ((size_t)(b * 9216) + px) * 128 + 64 + u * 16;
        *(int4v*)dst = *(int4v*)&tmp[0];
        *(int4v*)(dst + 8) = *(int4v*)&tmp[8];
    }
}

// ---------------------------------------------------------------------------
// Fused weight prepack. Standard convs: w[oc][cin][3][3] -> wp[cc][kk][kg][CoutP][8]
__device__ __forceinline__ void prep_one(const float* __restrict__ w,
        ushort* __restrict__ wp, int u, int Cin, int CoutR, int CoutP) {
    int oc = u % CoutP; int t = u / CoutP;
    int kg = t & 3; t >>= 2;
    int kk = t % 9; int cc = t / 9;
    alignas(16) ushort tmp[8];
    for (int j = 0; j < 8; ++j) {
        int c = cc * 32 + kg * 8 + j;
        float v = (oc < CoutR) ? w[((size_t)oc * Cin + c) * 9 + kk] : 0.f;
        tmp[j] = f2bf(v);
    }
    *(int4v*)(wp + (size_t)u * 8) = *(int4v*)tmp;
}

__global__ __launch_bounds__(256) void prepack_all_k(
        const float* __restrict__ w1, const float* __restrict__ w2,
        const float* __restrict__ w3, const float* __restrict__ wom,
        const float* __restrict__ wd, const float* __restrict__ wf,
        ushort* __restrict__ w1p, ushort* __restrict__ w2p,
        ushort* __restrict__ w3p, ushort* __restrict__ womp,
        ushort* __restrict__ wdp, ushort* __restrict__ wfp) {
    int u = blockIdx.x * 256 + threadIdx.x;
    if (u < 9216) prep_one(w1, w1p, u, 128, 64, 64);
    else if (u < 18432) prep_one(w2, w2p, u - 9216, 128, 64, 64);
    else if (u < 23040) prep_one(w3, w3p, u - 18432, 64, 64, 64);
    else if (u < 39168) prep_one(wom, womp, u - 23040, 64, 216, 224);
    else if (u < 43776) {
        int v = u - 39168;                    // [gkk*64 + oc][8], k=(g*9+kk)*8+cg
        int oc = v & 63; int gkk = v >> 6;
        int g = gkk / 9, kk = gkk % 9;
        alignas(16) ushort tmp[8];
        for (int j = 0; j < 8; ++j)
            tmp[j] = f2bf(wd[((size_t)oc * 64 + g * 8 + j) * 9 + kk]);
        *(int4v*)(wdp + (size_t)v * 8) = *(int4v*)tmp;
    } else if (u < 52992) prep_one(wf, wfp, u - 43776, 128, 64, 64);
}

// ---------------------------------------------------------------------------
// MFMA 3x3 conv: per-wave MT*16 oc x 16 px, block = 8x8 px tile, MT oc-tiles.
// A-fragments read DIRECTLY from global prepacked weights (L1/L2-hot,
// block-invariant) — no weight LDS staging. 1-D grid with XCD-chunked
// swizzle (z fastest so oc-siblings sharing the act tile co-locate).
// grid = 144*4*NZ (divisible by 8).
template<int CIN, int MT, int NZ, bool LRELU, bool ST_F32, bool ST_CHL>
__global__ __launch_bounds__(256, 4) void conv_mfma_k(
        const ushort* __restrict__ xin,      // [b][9216][CIN] bf16
        const ushort* __restrict__ wp,       // [CIN/32][9][4][CoutP][8]
        const float* __restrict__ bias,
        float* __restrict__ outf,            // NCHW fp32
        ushort* __restrict__ chl,            // ch-last bf16
        int CoutR, int CoutP, int ochs, int ocoff) {
    constexpr int CC = CIN / 32;
    constexpr int OCN = MT * 16;
    __shared__ ushort s_act[4000];            // [100 px][40] (32 used + pad)

    int tid = threadIdx.x;
    int wv = tid >> 6, ln = tid & 63;
    int l15 = ln & 15, l4 = ln >> 4;

    constexpr int TOTAL = 144 * 4 * NZ;
    constexpr int CHUNK = TOTAL / 8;
    int bid = blockIdx.x;
    int nid = (bid & 7) * CHUNK + (bid >> 3);
    int zc = nid % NZ; int r1 = nid / NZ;
    int b = r1 & 3; int tile = r1 >> 2;
    int bx = (tile % 12) * 8, by = (tile / 12) * 8;
    int oc0 = zc * OCN;

    int px_l = wv * 16 + l15;                 // px in 8x8 tile
    int py = px_l >> 3, pxx = px_l & 7;
    int b_base = (py * 10 + pxx) * 40 + l4 * 8;

    // per-lane weight fragment base: lane (l4 = kg, l15 partial oc)
    const ushort* wlane = wp + ((size_t)l4 * CoutP + oc0 + l15) * 8;

    f32x4 acc[MT];
#pragma unroll
    for (int mt = 0; mt < MT; ++mt) acc[mt] = (f32x4){0.f, 0.f, 0.f, 0.f};

    for (int cc = 0; cc < CC; ++cc) {
        __syncthreads();
        // stage activation halo tile 10x10 x 32ch
        for (int i = tid; i < 400; i += 256) {
            int p = i >> 2, q = i & 3;
            int gy = by + (p / 10) - 1, gx = bx + (p % 10) - 1;
            int4v v = {0, 0, 0, 0};
            if ((unsigned)gy < 96u && (unsigned)gx < 96u)
                v = *(const int4v*)(xin +
                    ((size_t)(b * 9216 + gy * 96 + gx) * CIN + cc * 32 + q * 8));
            *(int4v*)(s_act + p * 40 + q * 8) = v;
        }
        __syncthreads();
#pragma unroll
        for (int kk = 0; kk < 9; ++kk) {
            bf16x8 bfrag = *(const bf16x8*)(s_act + b_base +
                               ((kk / 3) * 10 + (kk % 3)) * 40);
#pragma unroll
            for (int mt = 0; mt < MT; ++mt) {
                bf16x8 af = *(const bf16x8*)(wlane +
                    ((size_t)(cc * 36 + kk * 4) * CoutP + mt * 16) * 8);
                acc[mt] = __builtin_amdgcn_mfma_f32_16x16x32_bf16(
                    af, bfrag, acc[mt], 0, 0, 0);
            }
        }
    }

    int gy = by + py, gx = bx + pxx;
    size_t pxg = (size_t)b * 9216 + gy * 96 + gx;
#pragma unroll
    for (int mt = 0; mt < MT; ++mt) {
        ushort hb[4];
#pragma unroll
        for (int r = 0; r < 4; ++r) {
            int oc = oc0 + mt * 16 + l4 * 4 + r;
            float v = acc[mt][r] + ((oc < CoutR) ? bias[oc] : 0.f);
            if (LRELU) v = (v >= 0.f) ? v : 0.1f * v;
            hb[r] = f2bf(v);
            if (ST_F32 && oc < CoutR)
                outf[((size_t)b * CoutR + oc) * 9216 + gy * 96 + gx] = v;
        }
        if (ST_CHL) {
            uint2 pk;
            pk.x = (uint)hb[0] | ((uint)hb[1] << 16);
            pk.y = (uint)hb[2] | ((uint)hb[3] << 16);
            *(uint2*)(chl + pxg * ochs + ocoff + oc0 + mt * 16 + l4 * 4) = pk;
        }
    }
}

// ---------------------------------------------------------------------------
// Fused DCNv2, register-direct B fragments + split-K(4) + XCD px-band swizzle.
// Block = 4 waves, ALL on the same 16 px; wave kq handles gkk in
// [kq*18, kq*18+18) as 5 steps of 4 lanes-l4 (last step half-masked).
// om is channels-last [px][224] (oy | ox | mask-logit). grid = 2304.
__global__ __launch_bounds__(256, 8) void dcn_fused_k(
        const ushort* __restrict__ xcl,      // xin1 [b][px][128], src0 in [0:64]
        const ushort* __restrict__ om,       // [b][px][224] ch-last bf16
        const ushort* __restrict__ wdp,
        const float* __restrict__ bd, ushort* __restrict__ chl) {
    __shared__ float s_red[3][64][17];
    int tid = threadIdx.x;
    int kq = tid >> 6, ln = tid & 63;
    int l15 = ln & 15, l4 = ln >> 4;
    int bid = blockIdx.x;                     // 0..2303
    int nid = (bid & 7) * 288 + (bid >> 3);   // XCD-chunked swizzle
    int pxb = nid % 576; int b = nid / 576;
    int px = pxb * 16 + l15;
    int y = px / 96, xx = px % 96;

    f32x4 acc[4];
#pragma unroll
    for (int mt = 0; mt < 4; ++mt) acc[mt] = (f32x4){0.f, 0.f, 0.f, 0.f};
    const ushort* xb = xcl + (size_t)b * 9216 * 128;
    const ushort* omp_ = om + ((size_t)b * 9216 + px) * 224;

#pragma unroll
    for (int s = 0; s < 5; ++s) {
        int gl = s * 4 + l4;                  // 0..19 local k index
        int glc = (gl < 18) ? gl : 17;        // clamp for tail
        int gkk = kq * 18 + glc;
        int g = gkk / 9, kk = gkk % 9;
        float oy = bf2f(omp_[gkk]);
        float ox = bf2f(omp_[72 + gkk]);
        float ml = bf2f(omp_[144 + gkk]);
        float mm = (gl < 18) ? 1.f / (1.f + __expf(-ml)) : 0.f;
        float py = oy + (float)y + (float)(kk / 3 - 1);
        float pxf = ox + (float)xx + (float)(kk % 3 - 1);
        float yf = floorf(py), xf = floorf(pxf);
        float fy = py - yf, fx = pxf - xf;
        int iy0 = (int)yf, ix0 = (int)xf;
        int iy1 = iy0 + 1, ix1 = ix0 + 1;
        float vy0 = ((unsigned)iy0 < 96u) ? 1.f : 0.f;
        float vy1 = ((unsigned)iy1 < 96u) ? 1.f : 0.f;
        float vx0 = ((unsigned)ix0 < 96u) ? 1.f : 0.f;
        float vx1 = ((unsigned)ix1 < 96u) ? 1.f : 0.f;
        int cy0 = min(max(iy0, 0), 95), cy1 = min(max(iy1, 0), 95);
        int cx0 = min(max(ix0, 0), 95), cx1 = min(max(ix1, 0), 95);
        float w00 = (1.f - fy) * (1.f - fx) * vy0 * vx0 * mm;
        float w01 = (1.f - fy) * fx         * vy0 * vx1 * mm;
        float w10 = fy * (1.f - fx)         * vy1 * vx0 * mm;
        float w11 = fy * fx                 * vy1 * vx1 * mm;
        int i00 = cy0 * 96 + cx0, i01 = cy0 * 96 + cx1;
        int i10 = cy1 * 96 + cx0, i11 = cy1 * 96 + cx1;

        const ushort* xg = xb + g * 8;        // channel slice of group g
        union { int4v v; ushort us[8]; } r00, r01, r10, r11;
        r00.v = *(const int4v*)(xg + (size_t)i00 * 128);
        r01.v = *(const int4v*)(xg + (size_t)i01 * 128);
        r10.v = *(const int4v*)(xg + (size_t)i10 * 128);
        r11.v = *(const int4v*)(xg + (size_t)i11 * 128);

        union { ushort us[8]; bf16x8 v; } bu;
#pragma unroll
        for (int j = 0; j < 8; ++j) {
            float v = w00 * bf2f(r00.us[j]) + w01 * bf2f(r01.us[j]) +
                      w10 * bf2f(r10.us[j]) + w11 * bf2f(r11.us[j]);
            bu.us[j] = f2bf(v);
        }
#pragma unroll
        for (int mt = 0; mt < 4; ++mt) {
            bf16x8 af = *(const bf16x8*)(wdp +
                ((size_t)gkk * 64 + mt * 16 + l15) * 8);
            acc[mt] = __builtin_amdgcn_mfma_f32_16x16x32_bf16(
                af, bu.v, acc[mt], 0, 0, 0);
        }
    }

    // split-K reduce across the 4 waves
    if (kq) {
#pragma unroll
        for (int mt = 0; mt < 4; ++mt)
#pragma unroll
            for (int r = 0; r < 4; ++r)
                s_red[kq - 1][ln][mt * 4 + r] = acc[mt][r];
    }
    __syncthreads();
    if (kq == 0) {
        size_t pb = (size_t)b * 9216 + px;
#pragma unroll
        for (int mt = 0; mt < 4; ++mt) {
            ushort hb[4];
#pragma unroll
            for (int r = 0; r < 4; ++r) {
                int oc = mt * 16 + l4 * 4 + r;
                float v = acc[mt][r] + s_red[0][ln][mt * 4 + r]
                        + s_red[1][ln][mt * 4 + r] + s_red[2][ln][mt * 4 + r]
                        + bd[oc];
                hb[r] = f2bf(v);
            }
            uint2 pk;
            pk.x = (uint)hb[0] | ((uint)hb[1] << 16);
            pk.y = (uint)hb[2] | ((uint)hb[3] << 16);
            *(uint2*)(chl + pb * 128 + mt * 16 + l4 * 4) = pk;
        }
    }
}

// ---------------------------------------------------------------------------
extern "C" void kernel_launch(void* const* d_in, const int* in_sizes, int n_in,
                              void* d_out, int out_size, void* d_ws, size_t ws_size,
                              hipStream_t stream) {
    const float* src0  = (const float*)d_in[0];
    const float* src1  = (const float*)d_in[1];
    const float* l_off = (const float*)d_in[2];
    const float* l_fea = (const float*)d_in[3];
    const float* w1 = (const float*)d_in[4];   const float* b1 = (const float*)d_in[5];
    const float* w2 = (const float*)d_in[6];   const float* b2 = (const float*)d_in[7];
    const float* w3 = (const float*)d_in[8];   const float* b3 = (const float*)d_in[9];
    const float* wom = (const float*)d_in[10]; const float* bom = (const float*)d_in[11];
    const float* wd = (const float*)d_in[12];  const float* bd = (const float*)d_in[13];
    const float* wf = (const float*)d_in[14];  const float* bf = (const float*)d_in[15];

    // workspace schedule (lifetimes annotated; regions reused after death)
    char* W = (char*)d_ws;
    ushort* xin1 = (ushort*)(W + 0);          //  9,437,184 B  [b][px][128]; live to dcn
    ushort* xin2 = (ushort*)(W + 9437184);    //  9,437,184 B  dead after conv2
    ushort* xoff = (ushort*)(W + 9437184);    //  4,718,592 B  over xin2 (dead)
    ushort* xin3 = (ushort*)(W + 18874368);   //  4,718,592 B  dead after conv3
    ushort* omb  = (ushort*)(W + 14155776);   // 16,515,072 B  [b][px][224]; over xin3
    ushort* xin4 = (ushort*)(W + 30670848);   //  9,437,184 B  [b][px][128]
    ushort* w1p  = (ushort*)(W + 40108032);   // 147,456 B
    ushort* w2p  = (ushort*)(W + 40255488);   // 147,456 B
    ushort* w3p  = (ushort*)(W + 40402944);   //  73,728 B
    ushort* womp = (ushort*)(W + 40476672);   // 258,048 B
    ushort* wdp  = (ushort*)(W + 40734720);   //  73,728 B
    ushort* wfp  = (ushort*)(W + 40808448);   // 147,456 B -> 40.96 MB total

    float* out_off = (float*)d_out;
    float* out_fea = out_off + (size_t)4 * 64 * 9216;

    // fused weight prepack (52992 units)
    prepack_all_k<<<207, 256, 0, stream>>>(w1, w2, w3, wom, wd, wf,
                                           w1p, w2p, w3p, womp, wdp, wfp);
    // fused input packs: xin1, xin2[64:128] (lo*2), xin4[64:128] (lf)
    pack_combo_k<<<dim3(144, 4, 3), 256, 0, stream>>>(
        src0, src1, l_off, l_fea, xin1, xin2, xin4);

    // conv1: xin1 -> xin2[0:64] (lrelu, ch-last)
    conv_mfma_k<128, 2, 2, true, false, true><<<1152, 256, 0, stream>>>(
        xin1, w1p, b1, nullptr, xin2, 64, 64, 128, 0);
    // conv2: xin2 -> xin3 (lrelu, ch-last)
    conv_mfma_k<128, 2, 2, true, false, true><<<1152, 256, 0, stream>>>(
        xin2, w2p, b2, nullptr, xin3, 64, 64, 64, 0);
    // conv3: xin3 -> out_off (fp32 NCHW) + xoff (ch-last)
    conv_mfma_k<64, 2, 2, true, true, true><<<1152, 256, 0, stream>>>(
        xin3, w3p, b3, out_off, xoff, 64, 64, 64, 0);
    // om conv: xoff -> omb (ch-last [px][224], vectorized epilogue)
    conv_mfma_k<64, 2, 7, false, false, true><<<4032, 256, 0, stream>>>(
        xoff, womp, bom, nullptr, omb, 216, 224, 224, 0);
    // fused DCN -> xin4[0:64]  (samples xin1, reads omb ch-last)
    dcn_fused_k<<<2304, 256, 0, stream>>>(xin1, omb, wdp, bd, xin4);
    // fea conv: xin4 -> out_fea (fp32 NCHW, lrelu)
    conv_mfma_k<128, 2, 2, true, true, false><<<1152, 256, 0, stream>>>(
        xin4, wfp, bf, out_fea, nullptr, 64, 64, 0, 0);
}

// Round 6
// 161.598 us; speedup vs baseline: 1.0770x; 1.0770x over previous
//
#include <hip/hip_runtime.h>
#include <math.h>

typedef __attribute__((ext_vector_type(8))) short bf16x8;
typedef __attribute__((ext_vector_type(4))) float f32x4;
typedef __attribute__((ext_vector_type(4))) int int4v;

#define GL_LDS16(g, l) __builtin_amdgcn_global_load_lds( \
    (const __attribute__((address_space(1))) void*)(g), \
    (__attribute__((address_space(3))) void*)(l), 16, 0, 0)

__device__ __forceinline__ ushort f2bf(float f) {
    union { float f; unsigned u; } v; v.f = f;
    unsigned r = (v.u + 0x7fffu + ((v.u >> 16) & 1u)) >> 16;
    return (ushort)r;
}
__device__ __forceinline__ float bf2f(ushort h) {
    union { unsigned u; float f; } v; v.u = ((unsigned)h) << 16;
    return v.f;
}

// ---------------------------------------------------------------------------
// Fused packs: z=0 pack concat(src0,src1)->xin1[px][128];
//              z=1 up2(l_off)*2 -> xin2[px][64:128]; z=2 up2(l_fea) -> xin4[px][64:128]
__global__ __launch_bounds__(256) void pack_combo_k(
        const float* __restrict__ s0, const float* __restrict__ s1,
        const float* __restrict__ lo, const float* __restrict__ lf,
        ushort* __restrict__ xin1, ushort* __restrict__ xin2,
        ushort* __restrict__ xin4) {
    int b = blockIdx.y;
    int z = blockIdx.z;
    int px = blockIdx.x * 64 + (threadIdx.x & 63);
    int u = threadIdx.x >> 6;
    if (z == 0) {
        for (int half = 0; half < 2; ++half) {
            int cg = u + half * 4;
            alignas(16) ushort tmp[16];
            for (int i = 0; i < 16; ++i) {
                int c = cg * 16 + i;
                float v = (c < 64) ? s0[((size_t)(b * 64 + c)) * 9216 + px]
                                   : s1[((size_t)(b * 64 + c - 64)) * 9216 + px];
                tmp[i] = f2bf(v);
            }
            ushort* dst = xin1 + ((size_t)(b * 9216) + px) * 128 + cg * 16;
            *(int4v*)dst = *(int4v*)&tmp[0];
            *(int4v*)(dst + 8) = *(int4v*)&tmp[8];
        }
    } else {
        const float* in = (z == 1) ? lo : lf;
        float scale = (z == 1) ? 2.0f : 1.0f;
        ushort* xo = (z == 1) ? xin2 : xin4;
        int y = px / 96, x = px % 96;
        float sy = fmaxf(y * 0.5f - 0.25f, 0.f);
        float sx = fmaxf(x * 0.5f - 0.25f, 0.f);
        int y0 = (int)sy, x0 = (int)sx;
        float ty = sy - (float)y0, tx = sx - (float)x0;
        int y1 = min(y0 + 1, 47), x1 = min(x0 + 1, 47);
        alignas(16) ushort tmp[16];
        for (int i = 0; i < 16; ++i) {
            int c = u * 16 + i;
            const float* p = in + ((size_t)(b * 64 + c)) * 2304;
            float v00 = p[y0 * 48 + x0], v01 = p[y0 * 48 + x1];
            float v10 = p[y1 * 48 + x0], v11 = p[y1 * 48 + x1];
            float v = (v00 * (1.f - tx) + v01 * tx) * (1.f - ty)
                    + (v10 * (1.f - tx) + v11 * tx) * ty;
            tmp[i] = f2bf(v * scale);
        }
        ushort* dst = xo + ((size_t)(b * 9216) + px) * 128 + 64 + u * 16;
        *(int4v*)dst = *(int4v*)&tmp[0];
        *(int4v*)(dst + 8) = *(int4v*)&tmp[8];
    }
}

// ---------------------------------------------------------------------------
// Fused weight prepack + zero-guard init.
__device__ __forceinline__ void prep_one(const float* __restrict__ w,
        ushort* __restrict__ wp, int u, int Cin, int CoutR, int CoutP) {
    int oc = u % CoutP; int t = u / CoutP;
    int kg = t & 3; t >>= 2;
    int kk = t % 9; int cc = t / 9;
    alignas(16) ushort tmp[8];
    for (int j = 0; j < 8; ++j) {
        int c = cc * 32 + kg * 8 + j;
        float v = (oc < CoutR) ? w[((size_t)oc * Cin + c) * 9 + kk] : 0.f;
        tmp[j] = f2bf(v);
    }
    *(int4v*)(wp + (size_t)u * 8) = *(int4v*)tmp;
}

__global__ __launch_bounds__(256) void prepack_all_k(
        const float* __restrict__ w1, const float* __restrict__ w2,
        const float* __restrict__ w3, const float* __restrict__ wom,
        const float* __restrict__ wd, const float* __restrict__ wf,
        ushort* __restrict__ w1p, ushort* __restrict__ w2p,
        ushort* __restrict__ w3p, ushort* __restrict__ womp,
        ushort* __restrict__ wdp, ushort* __restrict__ wfp,
        float* __restrict__ zg) {
    int u = blockIdx.x * 256 + threadIdx.x;
    if (u < 9216) prep_one(w1, w1p, u, 128, 64, 64);
    else if (u < 18432) prep_one(w2, w2p, u - 9216, 128, 64, 64);
    else if (u < 23040) prep_one(w3, w3p, u - 18432, 64, 64, 64);
    else if (u < 39168) prep_one(wom, womp, u - 23040, 64, 216, 224);
    else if (u < 43776) {
        int v = u - 39168;                    // [gkk*64 + oc][8], k=(g*9+kk)*8+cg
        int oc = v & 63; int gkk = v >> 6;
        int g = gkk / 9, kk = gkk % 9;
        alignas(16) ushort tmp[8];
        for (int j = 0; j < 8; ++j)
            tmp[j] = f2bf(wd[((size_t)oc * 64 + g * 8 + j) * 9 + kk]);
        *(int4v*)(wdp + (size_t)v * 8) = *(int4v*)tmp;
    } else if (u < 52992) prep_one(wf, wfp, u - 43776, 128, 64, 64);
    else if (u < 53008) zg[u - 52992] = 0.f;  // 64-B zero guard
}

// ---------------------------------------------------------------------------
// MFMA 3x3 conv: per-wave MT*16 oc x 16 px, block = 8x8 px tile, MT oc-tiles.
// Activation staged via global_load_lds (500 16-B chunks; chunk q==4 is the
// 16-B row pad, loaded from a zero guard; OOB halo also -> guard). Double-
// buffered 2-phase: STAGE(cc+1) issued before MFMA(cc). A-fragments read
// directly from global prepacked weights (L1-hot, block-invariant).
// 1-D grid, XCD-chunked swizzle, b-major banding (aligned with dcn).
template<int CIN, int MT, int NZ, bool LRELU, bool ST_F32, bool ST_CHL>
__global__ __launch_bounds__(256, 4) void conv_mfma_k(
        const ushort* __restrict__ xin,      // [b][9216][CIN] bf16
        const ushort* __restrict__ wp,       // [CIN/32][9][4][CoutP][8]
        const float* __restrict__ bias,
        float* __restrict__ outf,            // NCHW fp32
        ushort* __restrict__ chl,            // ch-last bf16
        const ushort* __restrict__ zg,       // 64-B zero guard
        int CoutR, int CoutP, int ochs, int ocoff) {
    constexpr int CC = CIN / 32;
    constexpr int OCN = MT * 16;
    __shared__ ushort s_act[2][4096];         // [buf][100 rows x 40u]; 8 KB each

    int tid = threadIdx.x;
    int wv = tid >> 6, ln = tid & 63;
    int l15 = ln & 15, l4 = ln >> 4;

    constexpr int TOTAL = 144 * 4 * NZ;
    constexpr int CHUNK = TOTAL / 8;
    int bid = blockIdx.x;
    int nid = (bid & 7) * CHUNK + (bid >> 3);
    int zc = nid % NZ; int r1 = nid / NZ;
    int tile = r1 % 144; int b = r1 / 144;    // b-major banding
    int bx = (tile % 12) * 8, by = (tile / 12) * 8;
    int oc0 = zc * OCN;

    int px_l = wv * 16 + l15;                 // px in 8x8 tile
    int py = px_l >> 3, pxx = px_l & 7;
    int b_base = (py * 10 + pxx) * 40 + l4 * 8;

    const ushort* wlane = wp + ((size_t)l4 * CoutP + oc0 + l15) * 8;

    f32x4 acc[MT];
#pragma unroll
    for (int mt = 0; mt < MT; ++mt) acc[mt] = (f32x4){0.f, 0.f, 0.f, 0.f};

    // stage one 32-channel slice into buffer `buf` via global_load_lds
    auto STAGE = [&](int cc, int buf) {
        for (int i = tid; i < 500; i += 256) {
            int p = i / 5, q = i - p * 5;     // q==4 -> pad slot
            int gy = by + (p / 10) - 1, gx = bx + (p % 10) - 1;
            const ushort* src = zg;
            if (q < 4 && (unsigned)gy < 96u && (unsigned)gx < 96u)
                src = xin + ((size_t)(b * 9216 + gy * 96 + gx) * CIN
                             + cc * 32 + q * 8);
            GL_LDS16(src, s_act[buf] + (size_t)i * 8);
        }
    };

    STAGE(0, 0);
    __syncthreads();
    for (int cc = 0; cc < CC; ++cc) {
        int cur = cc & 1;
        if (cc + 1 < CC) STAGE(cc + 1, cur ^ 1);
#pragma unroll
        for (int kk = 0; kk < 9; ++kk) {
            bf16x8 bfrag = *(const bf16x8*)(s_act[cur] + b_base +
                               ((kk / 3) * 10 + (kk % 3)) * 40);
#pragma unroll
            for (int mt = 0; mt < MT; ++mt) {
                bf16x8 af = *(const bf16x8*)(wlane +
                    ((size_t)(cc * 36 + kk * 4) * CoutP + mt * 16) * 8);
                acc[mt] = __builtin_amdgcn_mfma_f32_16x16x32_bf16(
                    af, bfrag, acc[mt], 0, 0, 0);
            }
        }
        __syncthreads();                      // drains vmcnt for staged loads
    }

    int gy = by + py, gx = bx + pxx;
    size_t pxg = (size_t)b * 9216 + gy * 96 + gx;
#pragma unroll
    for (int mt = 0; mt < MT; ++mt) {
        ushort hb[4];
#pragma unroll
        for (int r = 0; r < 4; ++r) {
            int oc = oc0 + mt * 16 + l4 * 4 + r;
            float v = acc[mt][r] + ((oc < CoutR) ? bias[oc] : 0.f);
            if (LRELU) v = (v >= 0.f) ? v : 0.1f * v;
            hb[r] = f2bf(v);
            if (ST_F32 && oc < CoutR)
                outf[((size_t)b * CoutR + oc) * 9216 + gy * 96 + gx] = v;
        }
        if (ST_CHL) {
            uint2 pk;
            pk.x = (uint)hb[0] | ((uint)hb[1] << 16);
            pk.y = (uint)hb[2] | ((uint)hb[3] << 16);
            *(uint2*)(chl + pxg * ochs + ocoff + oc0 + mt * 16 + l4 * 4) = pk;
        }
    }
}

// ---------------------------------------------------------------------------
// Fused DCNv2, register-direct B fragments + split-K(4) + XCD px-band swizzle.
// Block = 4 waves, ALL on the same 16 px; wave kq handles gkk in
// [kq*18, kq*18+18) as 5 steps of 4 lanes-l4 (last step half-masked).
// om is channels-last [px][224] (oy | ox | mask-logit). grid = 2304.
// launch_bounds (256,4): keep ~64 VGPRs so all 4 corner gathers stay in flight.
__global__ __launch_bounds__(256, 4) void dcn_fused_k(
        const ushort* __restrict__ xcl,      // xin1 [b][px][128], src0 in [0:64]
        const ushort* __restrict__ om,       // [b][px][224] ch-last bf16
        const ushort* __restrict__ wdp,
        const float* __restrict__ bd, ushort* __restrict__ chl) {
    __shared__ float s_red[3][64][17];
    int tid = threadIdx.x;
    int kq = tid >> 6, ln = tid & 63;
    int l15 = ln & 15, l4 = ln >> 4;
    int bid = blockIdx.x;                     // 0..2303
    int nid = (bid & 7) * 288 + (bid >> 3);   // XCD-chunked swizzle
    int pxb = nid % 576; int b = nid / 576;   // b-major banding
    int px = pxb * 16 + l15;
    int y = px / 96, xx = px % 96;

    f32x4 acc[4];
#pragma unroll
    for (int mt = 0; mt < 4; ++mt) acc[mt] = (f32x4){0.f, 0.f, 0.f, 0.f};
    const ushort* xb = xcl + (size_t)b * 9216 * 128;
    const ushort* omp_ = om + ((size_t)b * 9216 + px) * 224;

#pragma unroll
    for (int s = 0; s < 5; ++s) {
        int gl = s * 4 + l4;                  // 0..19 local k index
        int glc = (gl < 18) ? gl : 17;        // clamp for tail
        int gkk = kq * 18 + glc;
        int g = gkk / 9, kk = gkk % 9;
        float oy = bf2f(omp_[gkk]);
        float ox = bf2f(omp_[72 + gkk]);
        float ml = bf2f(omp_[144 + gkk]);
        float mm = (gl < 18) ? 1.f / (1.f + __expf(-ml)) : 0.f;
        float py = oy + (float)y + (float)(kk / 3 - 1);
        float pxf = ox + (float)xx + (float)(kk % 3 - 1);
        float yf = floorf(py), xf = floorf(pxf);
        float fy = py - yf, fx = pxf - xf;
        int iy0 = (int)yf, ix0 = (int)xf;
        int iy1 = iy0 + 1, ix1 = ix0 + 1;
        float vy0 = ((unsigned)iy0 < 96u) ? 1.f : 0.f;
        float vy1 = ((unsigned)iy1 < 96u) ? 1.f : 0.f;
        float vx0 = ((unsigned)ix0 < 96u) ? 1.f : 0.f;
        float vx1 = ((unsigned)ix1 < 96u) ? 1.f : 0.f;
        int cy0 = min(max(iy0, 0), 95), cy1 = min(max(iy1, 0), 95);
        int cx0 = min(max(ix0, 0), 95), cx1 = min(max(ix1, 0), 95);
        float w00 = (1.f - fy) * (1.f - fx) * vy0 * vx0 * mm;
        float w01 = (1.f - fy) * fx         * vy0 * vx1 * mm;
        float w10 = fy * (1.f - fx)         * vy1 * vx0 * mm;
        float w11 = fy * fx                 * vy1 * vx1 * mm;
        int i00 = cy0 * 96 + cx0, i01 = cy0 * 96 + cx1;
        int i10 = cy1 * 96 + cx0, i11 = cy1 * 96 + cx1;

        const ushort* xg = xb + g * 8;        // channel slice of group g
        union { int4v v; ushort us[8]; } r00, r01, r10, r11;
        r00.v = *(const int4v*)(xg + (size_t)i00 * 128);
        r01.v = *(const int4v*)(xg + (size_t)i01 * 128);
        r10.v = *(const int4v*)(xg + (size_t)i10 * 128);
        r11.v = *(const int4v*)(xg + (size_t)i11 * 128);

        union { ushort us[8]; bf16x8 v; } bu;
#pragma unroll
        for (int j = 0; j < 8; ++j) {
            float v = w00 * bf2f(r00.us[j]) + w01 * bf2f(r01.us[j]) +
                      w10 * bf2f(r10.us[j]) + w11 * bf2f(r11.us[j]);
            bu.us[j] = f2bf(v);
        }
#pragma unroll
        for (int mt = 0; mt < 4; ++mt) {
            bf16x8 af = *(const bf16x8*)(wdp +
                ((size_t)gkk * 64 + mt * 16 + l15) * 8);
            acc[mt] = __builtin_amdgcn_mfma_f32_16x16x32_bf16(
                af, bu.v, acc[mt], 0, 0, 0);
        }
    }

    // split-K reduce across the 4 waves
    if (kq) {
#pragma unroll
        for (int mt = 0; mt < 4; ++mt)
#pragma unroll
            for (int r = 0; r < 4; ++r)
                s_red[kq - 1][ln][mt * 4 + r] = acc[mt][r];
    }
    __syncthreads();
    if (kq == 0) {
        size_t pb = (size_t)b * 9216 + px;
#pragma unroll
        for (int mt = 0; mt < 4; ++mt) {
            ushort hb[4];
#pragma unroll
            for (int r = 0; r < 4; ++r) {
                int oc = mt * 16 + l4 * 4 + r;
                float v = acc[mt][r] + s_red[0][ln][mt * 4 + r]
                        + s_red[1][ln][mt * 4 + r] + s_red[2][ln][mt * 4 + r]
                        + bd[oc];
                hb[r] = f2bf(v);
            }
            uint2 pk;
            pk.x = (uint)hb[0] | ((uint)hb[1] << 16);
            pk.y = (uint)hb[2] | ((uint)hb[3] << 16);
            *(uint2*)(chl + pb * 128 + mt * 16 + l4 * 4) = pk;
        }
    }
}

// ---------------------------------------------------------------------------
extern "C" void kernel_launch(void* const* d_in, const int* in_sizes, int n_in,
                              void* d_out, int out_size, void* d_ws, size_t ws_size,
                              hipStream_t stream) {
    const float* src0  = (const float*)d_in[0];
    const float* src1  = (const float*)d_in[1];
    const float* l_off = (const float*)d_in[2];
    const float* l_fea = (const float*)d_in[3];
    const float* w1 = (const float*)d_in[4];   const float* b1 = (const float*)d_in[5];
    const float* w2 = (const float*)d_in[6];   const float* b2 = (const float*)d_in[7];
    const float* w3 = (const float*)d_in[8];   const float* b3 = (const float*)d_in[9];
    const float* wom = (const float*)d_in[10]; const float* bom = (const float*)d_in[11];
    const float* wd = (const float*)d_in[12];  const float* bd = (const float*)d_in[13];
    const float* wf = (const float*)d_in[14];  const float* bf = (const float*)d_in[15];

    // workspace schedule (lifetimes annotated; regions reused after death)
    char* W = (char*)d_ws;
    ushort* xin1 = (ushort*)(W + 0);          //  9,437,184 B  [b][px][128]; live to dcn
    ushort* xin2 = (ushort*)(W + 9437184);    //  9,437,184 B  dead after conv2
    ushort* xoff = (ushort*)(W + 9437184);    //  4,718,592 B  over xin2 (dead)
    ushort* xin3 = (ushort*)(W + 18874368);   //  4,718,592 B  dead after conv3
    ushort* omb  = (ushort*)(W + 14155776);   // 16,515,072 B  [b][px][224]; over xin3
    ushort* xin4 = (ushort*)(W + 30670848);   //  9,437,184 B  [b][px][128]
    ushort* w1p  = (ushort*)(W + 40108032);   // 147,456 B
    ushort* w2p  = (ushort*)(W + 40255488);   // 147,456 B
    ushort* w3p  = (ushort*)(W + 40402944);   //  73,728 B
    ushort* womp = (ushort*)(W + 40476672);   // 258,048 B
    ushort* wdp  = (ushort*)(W + 40734720);   //  73,728 B
    ushort* wfp  = (ushort*)(W + 40808448);   // 147,456 B
    float*  zgrd = (float*)(W + 40955904);    //      64 B zero guard -> 40.96 MB

    float* out_off = (float*)d_out;
    float* out_fea = out_off + (size_t)4 * 64 * 9216;

    // fused weight prepack + guard zero (53008 units)
    prepack_all_k<<<208, 256, 0, stream>>>(w1, w2, w3, wom, wd, wf,
                                           w1p, w2p, w3p, womp, wdp, wfp, zgrd);
    // fused input packs: xin1, xin2[64:128] (lo*2), xin4[64:128] (lf)
    pack_combo_k<<<dim3(144, 4, 3), 256, 0, stream>>>(
        src0, src1, l_off, l_fea, xin1, xin2, xin4);

    const ushort* zg = (const ushort*)zgrd;
    // conv1: xin1 -> xin2[0:64] (lrelu, ch-last)
    conv_mfma_k<128, 2, 2, true, false, true><<<1152, 256, 0, stream>>>(
        xin1, w1p, b1, nullptr, xin2, zg, 64, 64, 128, 0);
    // conv2: xin2 -> xin3 (lrelu, ch-last)
    conv_mfma_k<128, 2, 2, true, false, true><<<1152, 256, 0, stream>>>(
        xin2, w2p, b2, nullptr, xin3, zg, 64, 64, 64, 0);
    // conv3: xin3 -> out_off (fp32 NCHW) + xoff (ch-last)
    conv_mfma_k<64, 2, 2, true, true, true><<<1152, 256, 0, stream>>>(
        xin3, w3p, b3, out_off, xoff, zg, 64, 64, 64, 0);
    // om conv: xoff -> omb (ch-last [px][224], vectorized epilogue)
    conv_mfma_k<64, 2, 7, false, false, true><<<4032, 256, 0, stream>>>(
        xoff, womp, bom, nullptr, omb, zg, 216, 224, 224, 0);
    // fused DCN -> xin4[0:64]  (samples xin1, reads omb ch-last)
    dcn_fused_k<<<2304, 256, 0, stream>>>(xin1, omb, wdp, bd, xin4);
    // fea conv: xin4 -> out_fea (fp32 NCHW, lrelu)
    conv_mfma_k<128, 2, 2, true, true, false><<<1152, 256, 0, stream>>>(
        xin4, wfp, bf, out_fea, nullptr, zg, 64, 64, 0, 0);
}

// Round 7
// 159.866 us; speedup vs baseline: 1.0887x; 1.0108x over previous
//
#include <hip/hip_runtime.h>
#include <math.h>

typedef __attribute__((ext_vector_type(8))) short bf16x8;
typedef __attribute__((ext_vector_type(4))) float f32x4;
typedef __attribute__((ext_vector_type(4))) int int4v;

#define GL_LDS16(g, l) __builtin_amdgcn_global_load_lds( \
    (const __attribute__((address_space(1))) void*)(g), \
    (__attribute__((address_space(3))) void*)(l), 16, 0, 0)

__device__ __forceinline__ ushort f2bf(float f) {
    union { float f; unsigned u; } v; v.f = f;
    unsigned r = (v.u + 0x7fffu + ((v.u >> 16) & 1u)) >> 16;
    return (ushort)r;
}
__device__ __forceinline__ float bf2f(ushort h) {
    union { unsigned u; float f; } v; v.u = ((unsigned)h) << 16;
    return v.f;
}

// ---------------------------------------------------------------------------
// Fused packs: z=0 pack concat(src0,src1)->xin1[px][128];
//              z=1 up2(l_off)*2 -> xin2[px][64:128]; z=2 up2(l_fea) -> xin4[px][64:128]
__global__ __launch_bounds__(256) void pack_combo_k(
        const float* __restrict__ s0, const float* __restrict__ s1,
        const float* __restrict__ lo, const float* __restrict__ lf,
        ushort* __restrict__ xin1, ushort* __restrict__ xin2,
        ushort* __restrict__ xin4) {
    int b = blockIdx.y;
    int z = blockIdx.z;
    int px = blockIdx.x * 64 + (threadIdx.x & 63);
    int u = threadIdx.x >> 6;
    if (z == 0) {
        for (int half = 0; half < 2; ++half) {
            int cg = u + half * 4;
            alignas(16) ushort tmp[16];
            for (int i = 0; i < 16; ++i) {
                int c = cg * 16 + i;
                float v = (c < 64) ? s0[((size_t)(b * 64 + c)) * 9216 + px]
                                   : s1[((size_t)(b * 64 + c - 64)) * 9216 + px];
                tmp[i] = f2bf(v);
            }
            ushort* dst = xin1 + ((size_t)(b * 9216) + px) * 128 + cg * 16;
            *(int4v*)dst = *(int4v*)&tmp[0];
            *(int4v*)(dst + 8) = *(int4v*)&tmp[8];
        }
    } else {
        const float* in = (z == 1) ? lo : lf;
        float scale = (z == 1) ? 2.0f : 1.0f;
        ushort* xo = (z == 1) ? xin2 : xin4;
        int y = px / 96, x = px % 96;
        float sy = fmaxf(y * 0.5f - 0.25f, 0.f);
        float sx = fmaxf(x * 0.5f - 0.25f, 0.f);
        int y0 = (int)sy, x0 = (int)sx;
        float ty = sy - (float)y0, tx = sx - (float)x0;
        int y1 = min(y0 + 1, 47), x1 = min(x0 + 1, 47);
        alignas(16) ushort tmp[16];
        for (int i = 0; i < 16; ++i) {
            int c = u * 16 + i;
            const float* p = in + ((size_t)(b * 64 + c)) * 2304;
            float v00 = p[y0 * 48 + x0], v01 = p[y0 * 48 + x1];
            float v10 = p[y1 * 48 + x0], v11 = p[y1 * 48 + x1];
            float v = (v00 * (1.f - tx) + v01 * tx) * (1.f - ty)
                    + (v10 * (1.f - tx) + v11 * tx) * ty;
            tmp[i] = f2bf(v * scale);
        }
        ushort* dst = xo + ((size_t)(b * 9216) + px) * 128 + 64 + u * 16;
        *(int4v*)dst = *(int4v*)&tmp[0];
        *(int4v*)(dst + 8) = *(int4v*)&tmp[8];
    }
}

// ---------------------------------------------------------------------------
// Fused weight prepack. Standard convs: w[oc][cin][3][3] -> wp[cc][kk][kg][CoutP][8]
// om conv gets a channel-PERMUTED layout: output channel p = gkk*4 + t
// (t in {oy,ox,ml,pad}) so the conv directly emits dcn-interleaved om.
__device__ __forceinline__ void prep_one(const float* __restrict__ w,
        ushort* __restrict__ wp, int u, int Cin, int CoutR, int CoutP) {
    int oc = u % CoutP; int t = u / CoutP;
    int kg = t & 3; t >>= 2;
    int kk = t % 9; int cc = t / 9;
    alignas(16) ushort tmp[8];
    for (int j = 0; j < 8; ++j) {
        int c = cc * 32 + kg * 8 + j;
        float v = (oc < CoutR) ? w[((size_t)oc * Cin + c) * 9 + kk] : 0.f;
        tmp[j] = f2bf(v);
    }
    *(int4v*)(wp + (size_t)u * 8) = *(int4v*)tmp;
}

__global__ __launch_bounds__(256) void prepack_all_k(
        const float* __restrict__ w1, const float* __restrict__ w2,
        const float* __restrict__ w3, const float* __restrict__ wom,
        const float* __restrict__ wd, const float* __restrict__ wf,
        const float* __restrict__ bom,
        ushort* __restrict__ w1p, ushort* __restrict__ w2p,
        ushort* __restrict__ w3p, ushort* __restrict__ womp,
        ushort* __restrict__ wdp, ushort* __restrict__ wfp,
        float* __restrict__ bpp, float* __restrict__ zg) {
    int u = blockIdx.x * 256 + threadIdx.x;
    if (u < 9216) prep_one(w1, w1p, u, 128, 64, 64);
    else if (u < 18432) prep_one(w2, w2p, u - 9216, 128, 64, 64);
    else if (u < 23040) prep_one(w3, w3p, u - 18432, 64, 64, 64);
    else if (u < 43776) {
        // om conv, permuted: units = 2cc*9kk*4kg*288 = 20736
        int v = u - 23040;
        int ocp = v % 288; int t = v / 288;
        int kg = t & 3; t >>= 2;
        int kk = t % 9; int cc = t / 9;
        int t3 = ocp & 3, gkkp = ocp >> 2;
        alignas(16) ushort tmp[8];
        for (int j = 0; j < 8; ++j) {
            int c = cc * 32 + kg * 8 + j;
            float vv = (t3 < 3) ? wom[((size_t)(t3 * 72 + gkkp) * 64 + c) * 9 + kk] : 0.f;
            tmp[j] = f2bf(vv);
        }
        *(int4v*)(womp + (size_t)v * 8) = *(int4v*)tmp;
    } else if (u < 48384) {
        int v = u - 43776;                    // [gkk*64 + oc][8], k=(g*9+kk)*8+cg
        int oc = v & 63; int gkk = v >> 6;
        int g = gkk / 9, kk = gkk % 9;
        alignas(16) ushort tmp[8];
        for (int j = 0; j < 8; ++j)
            tmp[j] = f2bf(wd[((size_t)oc * 64 + g * 8 + j) * 9 + kk]);
        *(int4v*)(wdp + (size_t)v * 8) = *(int4v*)tmp;
    } else if (u < 57600) prep_one(wf, wfp, u - 48384, 128, 64, 64);
    else if (u < 57888) {
        int ocp = u - 57600; int t3 = ocp & 3, gkkp = ocp >> 2;
        bpp[ocp] = (t3 < 3) ? bom[t3 * 72 + gkkp] : 0.f;
    } else if (u < 57904) zg[u - 57888] = 0.f;   // 64-B zero guard
}

// ---------------------------------------------------------------------------
// MFMA 3x3 conv: per-wave MT*16 oc x 16 px, block = 8x8 px tile, MT oc-tiles.
// Activation staged in 64-channel slices via global_load_lds (900 16-B chunks;
// chunk q==8 is the row pad from a zero guard; OOB halo also -> guard).
// CIN=64: single stage, ONE barrier, unbroken MFMA stream.
// CIN=128: 2 slices, double-buffered, 2 barriers total.
// A-fragments read directly from global prepacked weights (L1-hot).
template<int CIN, int MT, int NZ, bool LRELU, bool ST_F32, bool ST_CHL>
__global__ __launch_bounds__(256, 4) void conv_mfma_k(
        const ushort* __restrict__ xin,      // [b][9216][CIN] bf16
        const ushort* __restrict__ wp,       // [CIN/32][9][4][CoutP][8]
        const float* __restrict__ bias,
        float* __restrict__ outf,            // NCHW fp32
        ushort* __restrict__ chl,            // ch-last bf16
        const ushort* __restrict__ zg,       // 64-B zero guard
        int CoutR, int CoutP, int ochs, int ocoff) {
    constexpr int SL = CIN / 64;
    constexpr int OCN = MT * 16;
    __shared__ ushort s_act[SL][7200];        // [buf][100 rows x 72u] 14.4 KB each

    int tid = threadIdx.x;
    int wv = tid >> 6, ln = tid & 63;
    int l15 = ln & 15, l4 = ln >> 4;

    constexpr int TOTAL = 144 * 4 * NZ;
    constexpr int CHUNK = TOTAL / 8;
    int bid = blockIdx.x;
    int nid = (bid & 7) * CHUNK + (bid >> 3);
    int zc = nid % NZ; int r1 = nid / NZ;
    int tile = r1 % 144; int b = r1 / 144;    // b-major banding
    int bx = (tile % 12) * 8, by = (tile / 12) * 8;
    int oc0 = zc * OCN;

    int px_l = wv * 16 + l15;                 // px in 8x8 tile
    int py = px_l >> 3, pxx = px_l & 7;
    int b_base = (py * 10 + pxx) * 72 + l4 * 8;

    const ushort* wlane = wp + ((size_t)l4 * CoutP + oc0 + l15) * 8;

    f32x4 acc[MT];
#pragma unroll
    for (int mt = 0; mt < MT; ++mt) acc[mt] = (f32x4){0.f, 0.f, 0.f, 0.f};

    // stage one 64-channel slice into buffer `buf` via global_load_lds
    auto STAGE = [&](int sl, int buf) {
        for (int i = tid; i < 900; i += 256) {
            int p = i / 9, q = i - p * 9;     // q==8 -> pad slot
            int gy = by + (p / 10) - 1, gx = bx + (p % 10) - 1;
            const ushort* src = zg;
            if (q < 8 && (unsigned)gy < 96u && (unsigned)gx < 96u)
                src = xin + ((size_t)(b * 9216 + gy * 96 + gx) * CIN
                             + sl * 64 + q * 8);
            GL_LDS16(src, s_act[buf] + (size_t)i * 8);
        }
    };

    STAGE(0, 0);
    __syncthreads();
#pragma unroll
    for (int sl = 0; sl < SL; ++sl) {
        if (sl + 1 < SL) STAGE(sl + 1, (sl + 1) & 1);
#pragma unroll
        for (int cc2 = 0; cc2 < 2; ++cc2) {
#pragma unroll
            for (int kk = 0; kk < 9; ++kk) {
                bf16x8 bfrag = *(const bf16x8*)(s_act[sl & (SL - 1)] + b_base +
                                   ((kk / 3) * 10 + (kk % 3)) * 72 + cc2 * 32);
#pragma unroll
                for (int mt = 0; mt < MT; ++mt) {
                    bf16x8 af = *(const bf16x8*)(wlane +
                        ((size_t)((sl * 2 + cc2) * 36 + kk * 4) * CoutP + mt * 16) * 8);
                    acc[mt] = __builtin_amdgcn_mfma_f32_16x16x32_bf16(
                        af, bfrag, acc[mt], 0, 0, 0);
                }
            }
        }
        if (sl + 1 < SL) __syncthreads();     // drains staged loads for next buf
    }

    int gy = by + py, gx = bx + pxx;
    size_t pxg = (size_t)b * 9216 + gy * 96 + gx;
#pragma unroll
    for (int mt = 0; mt < MT; ++mt) {
        ushort hb[4];
#pragma unroll
        for (int r = 0; r < 4; ++r) {
            int oc = oc0 + mt * 16 + l4 * 4 + r;
            float v = acc[mt][r] + ((oc < CoutR) ? bias[oc] : 0.f);
            if (LRELU) v = (v >= 0.f) ? v : 0.1f * v;
            hb[r] = f2bf(v);
            if (ST_F32 && oc < CoutR)
                outf[((size_t)b * CoutR + oc) * 9216 + gy * 96 + gx] = v;
        }
        if (ST_CHL) {
            uint2 pk;
            pk.x = (uint)hb[0] | ((uint)hb[1] << 16);
            pk.y = (uint)hb[2] | ((uint)hb[3] << 16);
            *(uint2*)(chl + pxg * ochs + ocoff + oc0 + mt * 16 + l4 * 4) = pk;
        }
    }
}

// ---------------------------------------------------------------------------
// Fused DCNv2: register-direct B fragments, split-K(2), interleaved om.
// Block = 128 thr = 2 waves; wave kq handles gkk in [kq*36, kq*36+36)
// as 9 fully-unrolled steps of 4 (lane l4). om [px][288]: one dwordx2/step,
// all 9 hoisted up front. grid = 2304, XCD px-band swizzle.
__global__ __launch_bounds__(128, 4) void dcn_fused_k(
        const ushort* __restrict__ xcl,      // xin1 [b][px][128], src0 in [0:64]
        const ushort* __restrict__ om,       // [b][px][288] interleaved bf16
        const ushort* __restrict__ wdp,
        const float* __restrict__ bd, ushort* __restrict__ chl) {
    __shared__ float s_red[64][17];
    int tid = threadIdx.x;
    int kq = tid >> 6, ln = tid & 63;
    int l15 = ln & 15, l4 = ln >> 4;
    int bid = blockIdx.x;                     // 0..2303
    int nid = (bid & 7) * 288 + (bid >> 3);   // XCD-chunked swizzle
    int pxb = nid % 576; int b = nid / 576;   // b-major banding
    int px = pxb * 16 + l15;
    int y = px / 96, xx = px % 96;

    f32x4 acc[4];
#pragma unroll
    for (int mt = 0; mt < 4; ++mt) acc[mt] = (f32x4){0.f, 0.f, 0.f, 0.f};
    const ushort* xb = xcl + (size_t)b * 9216 * 128;
    const ushort* omp_ = om + ((size_t)b * 9216 + px) * 288 + kq * 144;

    // hoist all 9 om quads (oy,ox,ml,pad) into registers: one wait total
    uint2 ovv[9];
#pragma unroll
    for (int s = 0; s < 9; ++s)
        ovv[s] = *(const uint2*)(omp_ + (s * 4 + l4) * 4);

#pragma unroll
    for (int s = 0; s < 9; ++s) {
        int gkk = kq * 36 + s * 4 + l4;
        int g = gkk / 9, kk = gkk - g * 9;
        union { uint2 u; ushort us[4]; } ov; ov.u = ovv[s];
        float oy = bf2f(ov.us[0]);
        float ox = bf2f(ov.us[1]);
        float mm = 1.f / (1.f + __expf(-bf2f(ov.us[2])));
        float py = oy + (float)y + (float)(kk / 3 - 1);
        float pxf = ox + (float)xx + (float)(kk % 3 - 1);
        float yf = floorf(py), xf = floorf(pxf);
        float fy = py - yf, fx = pxf - xf;
        int iy0 = (int)yf, ix0 = (int)xf;
        int iy1 = iy0 + 1, ix1 = ix0 + 1;
        float vy0 = ((unsigned)iy0 < 96u) ? 1.f : 0.f;
        float vy1 = ((unsigned)iy1 < 96u) ? 1.f : 0.f;
        float vx0 = ((unsigned)ix0 < 96u) ? 1.f : 0.f;
        float vx1 = ((unsigned)ix1 < 96u) ? 1.f : 0.f;
        int cy0 = min(max(iy0, 0), 95), cy1 = min(max(iy1, 0), 95);
        int cx0 = min(max(ix0, 0), 95), cx1 = min(max(ix1, 0), 95);
        float w00 = (1.f - fy) * (1.f - fx) * vy0 * vx0 * mm;
        float w01 = (1.f - fy) * fx         * vy0 * vx1 * mm;
        float w10 = fy * (1.f - fx)         * vy1 * vx0 * mm;
        float w11 = fy * fx                 * vy1 * vx1 * mm;
        int i00 = cy0 * 96 + cx0, i01 = cy0 * 96 + cx1;
        int i10 = cy1 * 96 + cx0, i11 = cy1 * 96 + cx1;

        const ushort* xg = xb + g * 8;        // channel slice of group g
        union { int4v v; ushort us[8]; } r00, r01, r10, r11;
        r00.v = *(const int4v*)(xg + (size_t)i00 * 128);
        r01.v = *(const int4v*)(xg + (size_t)i01 * 128);
        r10.v = *(const int4v*)(xg + (size_t)i10 * 128);
        r11.v = *(const int4v*)(xg + (size_t)i11 * 128);

        union { ushort us[8]; bf16x8 v; } bu;
#pragma unroll
        for (int j = 0; j < 8; ++j) {
            float v = w00 * bf2f(r00.us[j]) + w01 * bf2f(r01.us[j]) +
                      w10 * bf2f(r10.us[j]) + w11 * bf2f(r11.us[j]);
            bu.us[j] = f2bf(v);
        }
#pragma unroll
        for (int mt = 0; mt < 4; ++mt) {
            bf16x8 af = *(const bf16x8*)(wdp +
                ((size_t)gkk * 64 + mt * 16 + l15) * 8);
            acc[mt] = __builtin_amdgcn_mfma_f32_16x16x32_bf16(
                af, bu.v, acc[mt], 0, 0, 0);
        }
    }

    // split-K reduce: kq=1 writes, kq=0 adds + stores
    if (kq) {
#pragma unroll
        for (int mt = 0; mt < 4; ++mt)
#pragma unroll
            for (int r = 0; r < 4; ++r)
                s_red[ln][mt * 4 + r] = acc[mt][r];
    }
    __syncthreads();
    if (!kq) {
        size_t pb = (size_t)b * 9216 + px;
#pragma unroll
        for (int mt = 0; mt < 4; ++mt) {
            ushort hb[4];
#pragma unroll
            for (int r = 0; r < 4; ++r) {
                int oc = mt * 16 + l4 * 4 + r;
                float v = acc[mt][r] + s_red[ln][mt * 4 + r] + bd[oc];
                hb[r] = f2bf(v);
            }
            uint2 pk;
            pk.x = (uint)hb[0] | ((uint)hb[1] << 16);
            pk.y = (uint)hb[2] | ((uint)hb[3] << 16);
            *(uint2*)(chl + pb * 128 + mt * 16 + l4 * 4) = pk;
        }
    }
}

// ---------------------------------------------------------------------------
extern "C" void kernel_launch(void* const* d_in, const int* in_sizes, int n_in,
                              void* d_out, int out_size, void* d_ws, size_t ws_size,
                              hipStream_t stream) {
    const float* src0  = (const float*)d_in[0];
    const float* src1  = (const float*)d_in[1];
    const float* l_off = (const float*)d_in[2];
    const float* l_fea = (const float*)d_in[3];
    const float* w1 = (const float*)d_in[4];   const float* b1 = (const float*)d_in[5];
    const float* w2 = (const float*)d_in[6];   const float* b2 = (const float*)d_in[7];
    const float* w3 = (const float*)d_in[8];   const float* b3 = (const float*)d_in[9];
    const float* wom = (const float*)d_in[10]; const float* bom = (const float*)d_in[11];
    const float* wd = (const float*)d_in[12];  const float* bd = (const float*)d_in[13];
    const float* wf = (const float*)d_in[14];  const float* bf = (const float*)d_in[15];

    // workspace schedule (lifetimes annotated; regions reused after death)
    char* W = (char*)d_ws;
    ushort* xin1 = (ushort*)(W + 0);          //  9,437,184 B  live to dcn
    ushort* xin2 = (ushort*)(W + 9437184);    //  9,437,184 B  dead after conv2
    ushort* xoff = (ushort*)(W + 9437184);    //  4,718,592 B  over xin2 (dead)
    ushort* xin3 = (ushort*)(W + 18874368);   //  4,718,592 B  dead after conv3
    ushort* omb  = (ushort*)(W + 23592960);   // 21,233,664 B  [b][px][288]
    ushort* xin4 = (ushort*)(W + 44826624);   //  9,437,184 B  [b][px][128]
    ushort* w1p  = (ushort*)(W + 54263808);   // 147,456 B
    ushort* w2p  = (ushort*)(W + 54411264);   // 147,456 B
    ushort* w3p  = (ushort*)(W + 54558720);   //  73,728 B
    ushort* womp = (ushort*)(W + 54632448);   // 331,776 B (288-wide permuted)
    ushort* wdp  = (ushort*)(W + 54964224);   //  73,728 B
    ushort* wfp  = (ushort*)(W + 55037952);   // 147,456 B
    float*  bpp  = (float*)(W + 55185408);    //   1,152 B permuted om bias
    float*  zgrd = (float*)(W + 55186560);    //      64 B zero guard -> 55.19 MB

    float* out_off = (float*)d_out;
    float* out_fea = out_off + (size_t)4 * 64 * 9216;

    // fused weight prepack + om bias permute + guard zero (57904 units)
    prepack_all_k<<<227, 256, 0, stream>>>(w1, w2, w3, wom, wd, wf, bom,
                                           w1p, w2p, w3p, womp, wdp, wfp,
                                           bpp, zgrd);
    // fused input packs: xin1, xin2[64:128] (lo*2), xin4[64:128] (lf)
    pack_combo_k<<<dim3(144, 4, 3), 256, 0, stream>>>(
        src0, src1, l_off, l_fea, xin1, xin2, xin4);

    const ushort* zg = (const ushort*)zgrd;
    // conv1: xin1 -> xin2[0:64] (lrelu, ch-last)
    conv_mfma_k<128, 2, 2, true, false, true><<<1152, 256, 0, stream>>>(
        xin1, w1p, b1, nullptr, xin2, zg, 64, 64, 128, 0);
    // conv2: xin2 -> xin3 (lrelu, ch-last)
    conv_mfma_k<128, 2, 2, true, false, true><<<1152, 256, 0, stream>>>(
        xin2, w2p, b2, nullptr, xin3, zg, 64, 64, 64, 0);
    // conv3: xin3 -> out_off (fp32 NCHW) + xoff (ch-last)
    conv_mfma_k<64, 2, 2, true, true, true><<<1152, 256, 0, stream>>>(
        xin3, w3p, b3, out_off, xoff, zg, 64, 64, 64, 0);
    // om conv: xoff -> omb interleaved [px][288] (permuted weights/bias)
    conv_mfma_k<64, 2, 9, false, false, true><<<5184, 256, 0, stream>>>(
        xoff, womp, bpp, nullptr, omb, zg, 288, 288, 288, 0);
    // fused DCN -> xin4[0:64]  (samples xin1, reads omb interleaved)
    dcn_fused_k<<<2304, 128, 0, stream>>>(xin1, omb, wdp, bd, xin4);
    // fea conv: xin4 -> out_fea (fp32 NCHW, lrelu)
    conv_mfma_k<128, 2, 2, true, true, false><<<1152, 256, 0, stream>>>(
        xin4, wfp, bf, out_fea, nullptr, zg, 64, 64, 0, 0);
}

// Round 8
// 146.663 us; speedup vs baseline: 1.1867x; 1.0900x over previous
//
#include <hip/hip_runtime.h>
#include <math.h>

typedef __attribute__((ext_vector_type(8))) short bf16x8;
typedef __attribute__((ext_vector_type(4))) float f32x4;
typedef __attribute__((ext_vector_type(4))) int int4v;

#define GL_LDS16(g, l) __builtin_amdgcn_global_load_lds( \
    (const __attribute__((address_space(1))) void*)(g), \
    (__attribute__((address_space(3))) void*)(l), 16, 0, 0)

__device__ __forceinline__ ushort f2bf(float f) {
    union { float f; unsigned u; } v; v.f = f;
    unsigned r = (v.u + 0x7fffu + ((v.u >> 16) & 1u)) >> 16;
    return (ushort)r;
}
__device__ __forceinline__ float bf2f(ushort h) {
    union { unsigned u; float f; } v; v.u = ((unsigned)h) << 16;
    return v.f;
}

// ---------------------------------------------------------------------------
// Weight prepack helper: w[oc][cin][3][3] -> wp[cc][kk][kg][CoutP][8]
__device__ __forceinline__ void prep_one(const float* __restrict__ w,
        ushort* __restrict__ wp, int u, int Cin, int CoutR, int CoutP) {
    int oc = u % CoutP; int t = u / CoutP;
    int kg = t & 3; t >>= 2;
    int kk = t % 9; int cc = t / 9;
    alignas(16) ushort tmp[8];
    for (int j = 0; j < 8; ++j) {
        int c = cc * 32 + kg * 8 + j;
        float v = (oc < CoutR) ? w[((size_t)oc * Cin + c) * 9 + kk] : 0.f;
        tmp[j] = f2bf(v);
    }
    *(int4v*)(wp + (size_t)u * 8) = *(int4v*)tmp;
}

// ---------------------------------------------------------------------------
// Fused packs + prepack:
//  z=0: pack concat(src0,src1)->xin1[px][128]  AND xg1[b][g][px][8] (src0 groups)
//  z=1: up2(l_off)*2 -> xin2[px][64:128]; z=2: up2(l_fea) -> xin4[px][64:128]
//  z=3: all weight prepacks + om bias permute + zero guard
__global__ __launch_bounds__(256) void pack_combo_k(
        const float* __restrict__ s0, const float* __restrict__ s1,
        const float* __restrict__ lo, const float* __restrict__ lf,
        const float* __restrict__ w1, const float* __restrict__ w2,
        const float* __restrict__ w3, const float* __restrict__ wom,
        const float* __restrict__ wd, const float* __restrict__ wf,
        const float* __restrict__ bom,
        ushort* __restrict__ xin1, ushort* __restrict__ xin2,
        ushort* __restrict__ xin4, ushort* __restrict__ xg1,
        ushort* __restrict__ w1p, ushort* __restrict__ w2p,
        ushort* __restrict__ w3p, ushort* __restrict__ womp,
        ushort* __restrict__ wdp, ushort* __restrict__ wfp,
        float* __restrict__ bpp, float* __restrict__ zg) {
    int b = blockIdx.y;
    int z = blockIdx.z;
    int px = blockIdx.x * 64 + (threadIdx.x & 63);
    int u = threadIdx.x >> 6;
    if (z == 0) {
        for (int half = 0; half < 2; ++half) {
            int cg = u + half * 4;
            alignas(16) ushort tmp[16];
            for (int i = 0; i < 16; ++i) {
                int c = cg * 16 + i;
                float v = (c < 64) ? s0[((size_t)(b * 64 + c)) * 9216 + px]
                                   : s1[((size_t)(b * 64 + c - 64)) * 9216 + px];
                tmp[i] = f2bf(v);
            }
            ushort* dst = xin1 + ((size_t)(b * 9216) + px) * 128 + cg * 16;
            *(int4v*)dst = *(int4v*)&tmp[0];
            *(int4v*)(dst + 8) = *(int4v*)&tmp[8];
            if (half == 0) {
                // gather copy: groups g = cg*2, cg*2+1
                ushort* gdst = xg1 + (((size_t)(b * 8 + cg * 2) * 9216) + px) * 8;
                *(int4v*)gdst = *(int4v*)&tmp[0];
                *(int4v*)(gdst + 9216 * 8) = *(int4v*)&tmp[8];
            }
        }
    } else if (z < 3) {
        const float* in = (z == 1) ? lo : lf;
        float scale = (z == 1) ? 2.0f : 1.0f;
        ushort* xo = (z == 1) ? xin2 : xin4;
        int y = px / 96, x = px % 96;
        float sy = fmaxf(y * 0.5f - 0.25f, 0.f);
        float sx = fmaxf(x * 0.5f - 0.25f, 0.f);
        int y0 = (int)sy, x0 = (int)sx;
        float ty = sy - (float)y0, tx = sx - (float)x0;
        int y1 = min(y0 + 1, 47), x1 = min(x0 + 1, 47);
        alignas(16) ushort tmp[16];
        for (int i = 0; i < 16; ++i) {
            int c = u * 16 + i;
            const float* p = in + ((size_t)(b * 64 + c)) * 2304;
            float v00 = p[y0 * 48 + x0], v01 = p[y0 * 48 + x1];
            float v10 = p[y1 * 48 + x0], v11 = p[y1 * 48 + x1];
            float v = (v00 * (1.f - tx) + v01 * tx) * (1.f - ty)
                    + (v10 * (1.f - tx) + v11 * tx) * ty;
            tmp[i] = f2bf(v * scale);
        }
        ushort* dst = xo + ((size_t)(b * 9216) + px) * 128 + 64 + u * 16;
        *(int4v*)dst = *(int4v*)&tmp[0];
        *(int4v*)(dst + 8) = *(int4v*)&tmp[8];
    } else {
        // prepack: 60240 units over 576 blocks
        int uu = (blockIdx.x + 144 * blockIdx.y) * 256 + threadIdx.x;
        if (uu < 9216) prep_one(w1, w1p, uu, 128, 64, 64);
        else if (uu < 18432) prep_one(w2, w2p, uu - 9216, 128, 64, 64);
        else if (uu < 23040) prep_one(w3, w3p, uu - 18432, 64, 64, 64);
        else if (uu < 46080) {
            // om conv, permuted+padded: CoutP=320, oc p = gkk*4 + t3
            int v = uu - 23040;
            int ocp = v % 320; int t = v / 320;
            int kg = t & 3; t >>= 2;
            int kk = t % 9; int cc = t / 9;
            int t3 = ocp & 3, gkkp = ocp >> 2;
            alignas(16) ushort tmp[8];
            for (int j = 0; j < 8; ++j) {
                int c = cc * 32 + kg * 8 + j;
                float vv = (t3 < 3 && gkkp < 72)
                    ? wom[((size_t)(t3 * 72 + gkkp) * 64 + c) * 9 + kk] : 0.f;
                tmp[j] = f2bf(vv);
            }
            *(int4v*)(womp + (size_t)v * 8) = *(int4v*)tmp;
        } else if (uu < 50688) {
            int v = uu - 46080;               // [gkk*64 + oc][8], k=(g*9+kk)*8+cg
            int oc = v & 63; int gkk = v >> 6;
            int g = gkk / 9, kk = gkk % 9;
            alignas(16) ushort tmp[8];
            for (int j = 0; j < 8; ++j)
                tmp[j] = f2bf(wd[((size_t)oc * 64 + g * 8 + j) * 9 + kk]);
            *(int4v*)(wdp + (size_t)v * 8) = *(int4v*)tmp;
        } else if (uu < 59904) prep_one(wf, wfp, uu - 50688, 128, 64, 64);
        else if (uu < 60224) {
            int ocp = uu - 59904; int t3 = ocp & 3, gkkp = ocp >> 2;
            bpp[ocp] = (t3 < 3 && gkkp < 72) ? bom[t3 * 72 + gkkp] : 0.f;
        } else if (uu < 60240) zg[uu - 60224] = 0.f;  // 64-B zero guard
    }
}

// ---------------------------------------------------------------------------
// MFMA 3x3 conv: per-wave MT*16 oc x 16 px, block = 8x8 px tile.
// Activation staged in 64-channel slices via global_load_lds; zero-guard for
// pad/OOB. CIN=64: single stage (one barrier). CIN=128: 2 slices dbuf.
// A-fragments read directly from global prepacked weights (L1-hot).
template<int CIN, int MT, int NZ, bool LRELU, bool ST_F32, bool ST_CHL>
__global__ __launch_bounds__(256, 4) void conv_mfma_k(
        const ushort* __restrict__ xin,      // [b][9216][CIN] bf16
        const ushort* __restrict__ wp,       // [CIN/32][9][4][CoutP][8]
        const float* __restrict__ bias,
        float* __restrict__ outf,            // NCHW fp32
        ushort* __restrict__ chl,            // ch-last bf16
        const ushort* __restrict__ zg,       // 64-B zero guard
        int CoutR, int CoutP, int ochs, int ocoff) {
    constexpr int SL = CIN / 64;
    constexpr int OCN = MT * 16;
    __shared__ ushort s_act[SL][7200];        // [buf][100 rows x 72u] 14.4 KB each

    int tid = threadIdx.x;
    int wv = tid >> 6, ln = tid & 63;
    int l15 = ln & 15, l4 = ln >> 4;

    constexpr int TOTAL = 144 * 4 * NZ;
    constexpr int CHUNK = TOTAL / 8;
    int bid = blockIdx.x;
    int nid = (bid & 7) * CHUNK + (bid >> 3);
    int zc = nid % NZ; int r1 = nid / NZ;
    int tile = r1 % 144; int b = r1 / 144;    // b-major banding
    int bx = (tile % 12) * 8, by = (tile / 12) * 8;
    int oc0 = zc * OCN;

    int px_l = wv * 16 + l15;                 // px in 8x8 tile
    int py = px_l >> 3, pxx = px_l & 7;
    int b_base = (py * 10 + pxx) * 72 + l4 * 8;

    const ushort* wlane = wp + ((size_t)l4 * CoutP + oc0 + l15) * 8;

    f32x4 acc[MT];
#pragma unroll
    for (int mt = 0; mt < MT; ++mt) acc[mt] = (f32x4){0.f, 0.f, 0.f, 0.f};

    auto STAGE = [&](int sl, int buf) {
        for (int i = tid; i < 900; i += 256) {
            int p = i / 9, q = i - p * 9;     // q==8 -> pad slot
            int gy = by + (p / 10) - 1, gx = bx + (p % 10) - 1;
            const ushort* src = zg;
            if (q < 8 && (unsigned)gy < 96u && (unsigned)gx < 96u)
                src = xin + ((size_t)(b * 9216 + gy * 96 + gx) * CIN
                             + sl * 64 + q * 8);
            GL_LDS16(src, s_act[buf] + (size_t)i * 8);
        }
    };

    STAGE(0, 0);
    __syncthreads();
#pragma unroll
    for (int sl = 0; sl < SL; ++sl) {
        if (sl + 1 < SL) STAGE(sl + 1, (sl + 1) & 1);
#pragma unroll
        for (int cc2 = 0; cc2 < 2; ++cc2) {
#pragma unroll
            for (int kk = 0; kk < 9; ++kk) {
                bf16x8 bfrag = *(const bf16x8*)(s_act[sl & (SL - 1)] + b_base +
                                   ((kk / 3) * 10 + (kk % 3)) * 72 + cc2 * 32);
#pragma unroll
                for (int mt = 0; mt < MT; ++mt) {
                    bf16x8 af = *(const bf16x8*)(wlane +
                        ((size_t)((sl * 2 + cc2) * 36 + kk * 4) * CoutP + mt * 16) * 8);
                    acc[mt] = __builtin_amdgcn_mfma_f32_16x16x32_bf16(
                        af, bfrag, acc[mt], 0, 0, 0);
                }
            }
        }
        if (sl + 1 < SL) __syncthreads();
    }

    int gy = by + py, gx = bx + pxx;
    size_t pxg = (size_t)b * 9216 + gy * 96 + gx;
#pragma unroll
    for (int mt = 0; mt < MT; ++mt) {
        int ocb = oc0 + mt * 16 + l4 * 4;
        ushort hb[4];
#pragma unroll
        for (int r = 0; r < 4; ++r) {
            int oc = ocb + r;
            float v = acc[mt][r] + ((oc < CoutR) ? bias[oc] : 0.f);
            if (LRELU) v = (v >= 0.f) ? v : 0.1f * v;
            hb[r] = f2bf(v);
            if (ST_F32 && oc < CoutR)
                outf[((size_t)b * CoutR + oc) * 9216 + gy * 96 + gx] = v;
        }
        if (ST_CHL && ocb < CoutR) {
            uint2 pk;
            pk.x = (uint)hb[0] | ((uint)hb[1] << 16);
            pk.y = (uint)hb[2] | ((uint)hb[3] << 16);
            *(uint2*)(chl + pxg * ochs + ocoff + ocb) = pk;
        }
    }
}

// ---------------------------------------------------------------------------
// Fused DCNv2: gather-layout xg1 [b][g][px][8] (x-corners adjacent -> paired
// 16B loads, line-coalesced across lanes), split-K(2), interleaved om,
// distance-1 software-pipelined PREP. grid = 2304 x 128 thr.
__global__ __launch_bounds__(128, 4) void dcn_fused_k(
        const ushort* __restrict__ xg1,      // [b][8][9216][8] bf16
        const ushort* __restrict__ om,       // [b][px][288] interleaved bf16
        const ushort* __restrict__ wdp,
        const float* __restrict__ bd, ushort* __restrict__ chl) {
    __shared__ float s_red[64][17];
    int tid = threadIdx.x;
    int kq = tid >> 6, ln = tid & 63;
    int l15 = ln & 15, l4 = ln >> 4;
    int bid = blockIdx.x;                     // 0..2303
    int nid = (bid & 7) * 288 + (bid >> 3);   // XCD-chunked swizzle
    int pxb = nid % 576; int b = nid / 576;   // b-major banding
    int px = pxb * 16 + l15;
    int y = px / 96, xx = px % 96;

    f32x4 acc[4];
#pragma unroll
    for (int mt = 0; mt < 4; ++mt) acc[mt] = (f32x4){0.f, 0.f, 0.f, 0.f};
    const ushort* omp_ = om + ((size_t)b * 9216 + px) * 288 + kq * 144;

    // hoist the 9 om quads (oy,ox,ml,pad): one latency wait total
    uint2 ovv[9];
#pragma unroll
    for (int s = 0; s < 9; ++s)
        ovv[s] = *(const uint2*)(omp_ + s * 16 + l4 * 4);

    int4v Abuf[2][4];
    float cwbuf[2][4];

    auto PREP = [&](int s, int4v* A, float* cw) {
        int gkk = kq * 36 + s * 4 + l4;
        int g = gkk / 9, kk = gkk - g * 9;
        union { uint2 u; ushort us[4]; } ov; ov.u = ovv[s];
        float oy = bf2f(ov.us[0]), ox = bf2f(ov.us[1]);
        float mm = 1.f / (1.f + __expf(-bf2f(ov.us[2])));
        float py = oy + (float)(y + kk / 3 - 1);
        float pxf = ox + (float)(xx + kk % 3 - 1);
        float yf = floorf(py), xf = floorf(pxf);
        float fy = py - yf, fx = pxf - xf;
        int iy0 = (int)yf, ix0 = (int)xf;
        int iy1 = iy0 + 1, ix1 = ix0 + 1;
        float vy0 = ((unsigned)iy0 < 96u) ? 1.f : 0.f;
        float vy1 = ((unsigned)iy1 < 96u) ? 1.f : 0.f;
        float vx0 = ((unsigned)ix0 < 96u) ? 1.f : 0.f;
        float vx1 = ((unsigned)ix1 < 96u) ? 1.f : 0.f;
        int r0 = min(max(iy0, 0), 95), r1 = min(max(iy1, 0), 95);
        int lb = min(max(ix0, 0), 94);
        // half-selects: which 16B cell (lb or lb+1) each x-corner lives in
        float h0 = (float)min(max(ix0 - lb, 0), 1);   // 1 only when ix0==95
        float h1 = (float)min(max(ix1 - lb, 0), 1);   // 0 only when ix0==-1
        float wx0 = (1.f - fx) * vx0, wx1 = fx * vx1;
        float xw0 = wx0 * (1.f - h0) + wx1 * (1.f - h1);
        float xw1 = wx0 * h0 + wx1 * h1;
        float rw0 = (1.f - fy) * vy0 * mm, rw1 = fy * vy1 * mm;
        cw[0] = rw0 * xw0; cw[1] = rw0 * xw1;
        cw[2] = rw1 * xw0; cw[3] = rw1 * xw1;
        const ushort* gp = xg1 + ((size_t)(b * 8 + g) * 9216) * 8;
        const ushort* p0 = gp + ((size_t)(r0 * 96 + lb)) * 8;
        const ushort* p1 = gp + ((size_t)(r1 * 96 + lb)) * 8;
        A[0] = *(const int4v*)p0;
        A[1] = *(const int4v*)(p0 + 8);
        A[2] = *(const int4v*)p1;
        A[3] = *(const int4v*)(p1 + 8);
    };

    PREP(0, Abuf[0], cwbuf[0]);
#pragma unroll
    for (int s = 0; s < 9; ++s) {
        if (s + 1 < 9) PREP(s + 1, Abuf[(s + 1) & 1], cwbuf[(s + 1) & 1]);
        const int4v* A = Abuf[s & 1];
        const float* cw = cwbuf[s & 1];
        union { int4v v; ushort us[8]; } a0, a1, b0, b1;
        a0.v = A[0]; a1.v = A[1]; b0.v = A[2]; b1.v = A[3];
        union { ushort us[8]; bf16x8 v; } bu;
#pragma unroll
        for (int j = 0; j < 8; ++j) {
            float v = cw[0] * bf2f(a0.us[j]) + cw[1] * bf2f(a1.us[j]) +
                      cw[2] * bf2f(b0.us[j]) + cw[3] * bf2f(b1.us[j]);
            bu.us[j] = f2bf(v);
        }
        int gkk = kq * 36 + s * 4 + l4;
#pragma unroll
        for (int mt = 0; mt < 4; ++mt) {
            bf16x8 af = *(const bf16x8*)(wdp +
                ((size_t)gkk * 64 + mt * 16 + l15) * 8);
            acc[mt] = __builtin_amdgcn_mfma_f32_16x16x32_bf16(
                af, bu.v, acc[mt], 0, 0, 0);
        }
    }

    // split-K reduce: kq=1 writes, kq=0 adds + stores
    if (kq) {
#pragma unroll
        for (int mt = 0; mt < 4; ++mt)
#pragma unroll
            for (int r = 0; r < 4; ++r)
                s_red[ln][mt * 4 + r] = acc[mt][r];
    }
    __syncthreads();
    if (!kq) {
        size_t pb = (size_t)b * 9216 + px;
#pragma unroll
        for (int mt = 0; mt < 4; ++mt) {
            ushort hb[4];
#pragma unroll
            for (int r = 0; r < 4; ++r) {
                int oc = mt * 16 + l4 * 4 + r;
                float v = acc[mt][r] + s_red[ln][mt * 4 + r] + bd[oc];
                hb[r] = f2bf(v);
            }
            uint2 pk;
            pk.x = (uint)hb[0] | ((uint)hb[1] << 16);
            pk.y = (uint)hb[2] | ((uint)hb[3] << 16);
            *(uint2*)(chl + pb * 128 + mt * 16 + l4 * 4) = pk;
        }
    }
}

// ---------------------------------------------------------------------------
extern "C" void kernel_launch(void* const* d_in, const int* in_sizes, int n_in,
                              void* d_out, int out_size, void* d_ws, size_t ws_size,
                              hipStream_t stream) {
    const float* src0  = (const float*)d_in[0];
    const float* src1  = (const float*)d_in[1];
    const float* l_off = (const float*)d_in[2];
    const float* l_fea = (const float*)d_in[3];
    const float* w1 = (const float*)d_in[4];   const float* b1 = (const float*)d_in[5];
    const float* w2 = (const float*)d_in[6];   const float* b2 = (const float*)d_in[7];
    const float* w3 = (const float*)d_in[8];   const float* b3 = (const float*)d_in[9];
    const float* wom = (const float*)d_in[10]; const float* bom = (const float*)d_in[11];
    const float* wd = (const float*)d_in[12];  const float* bd = (const float*)d_in[13];
    const float* wf = (const float*)d_in[14];  const float* bf = (const float*)d_in[15];

    // workspace schedule (lifetimes annotated; regions reused after death)
    char* W = (char*)d_ws;
    ushort* xin1 = (ushort*)(W + 0);          //  9,437,184 B  live to conv1
    ushort* xin2 = (ushort*)(W + 9437184);    //  9,437,184 B  dead after conv2
    ushort* xoff = (ushort*)(W + 9437184);    //  4,718,592 B  over xin2 (dead)
    ushort* xin3 = (ushort*)(W + 18874368);   //  4,718,592 B  dead after conv3
    ushort* omb  = (ushort*)(W + 23592960);   // 21,233,664 B  [b][px][288]
    ushort* xin4 = (ushort*)(W + 44826624);   //  9,437,184 B  [b][px][128]
    ushort* xg1  = (ushort*)(W + 54263808);   //  4,718,592 B  [b][8][px][8]
    ushort* w1p  = (ushort*)(W + 58982400);   // 147,456 B
    ushort* w2p  = (ushort*)(W + 59129856);   // 147,456 B
    ushort* w3p  = (ushort*)(W + 59277312);   //  73,728 B
    ushort* womp = (ushort*)(W + 59351040);   // 368,640 B (320-wide permuted)
    ushort* wdp  = (ushort*)(W + 59719680);   //  73,728 B
    ushort* wfp  = (ushort*)(W + 59793408);   // 147,456 B
    float*  bpp  = (float*)(W + 59940864);    //   1,280 B permuted om bias
    float*  zgrd = (float*)(W + 59942144);    //      64 B zero guard -> 57.2 MB

    float* out_off = (float*)d_out;
    float* out_fea = out_off + (size_t)4 * 64 * 9216;

    // fused packs + prepack (z=3)
    pack_combo_k<<<dim3(144, 4, 4), 256, 0, stream>>>(
        src0, src1, l_off, l_fea, w1, w2, w3, wom, wd, wf, bom,
        xin1, xin2, xin4, xg1, w1p, w2p, w3p, womp, wdp, wfp, bpp, zgrd);

    const ushort* zg = (const ushort*)zgrd;
    // conv1: xin1 -> xin2[0:64] (lrelu, ch-last)
    conv_mfma_k<128, 2, 2, true, false, true><<<1152, 256, 0, stream>>>(
        xin1, w1p, b1, nullptr, xin2, zg, 64, 64, 128, 0);
    // conv2: xin2 -> xin3 (lrelu, ch-last)
    conv_mfma_k<128, 2, 2, true, false, true><<<1152, 256, 0, stream>>>(
        xin2, w2p, b2, nullptr, xin3, zg, 64, 64, 64, 0);
    // conv3: xin3 -> out_off (fp32 NCHW) + xoff (ch-last)
    conv_mfma_k<64, 2, 2, true, true, true><<<1152, 256, 0, stream>>>(
        xin3, w3p, b3, out_off, xoff, zg, 64, 64, 64, 0);
    // om conv: xoff -> omb interleaved [px][288] (permuted weights/bias, MT=4)
    conv_mfma_k<64, 4, 5, false, false, true><<<2880, 256, 0, stream>>>(
        xoff, womp, bpp, nullptr, omb, zg, 288, 320, 288, 0);
    // fused DCN -> xin4[0:64]  (samples xg1, reads omb interleaved)
    dcn_fused_k<<<2304, 128, 0, stream>>>(xg1, omb, wdp, bd, xin4);
    // fea conv: xin4 -> out_fea (fp32 NCHW, lrelu)
    conv_mfma_k<128, 2, 2, true, true, false><<<1152, 256, 0, stream>>>(
        xin4, wfp, bf, out_fea, nullptr, zg, 64, 64, 0, 0);
}